// Round 2
// baseline (3787.944 us; speedup 1.0000x reference)
//
#include <hip/hip_runtime.h>
#include <cstddef>

// Problem dims
static constexpr int B_  = 256;
static constexpr int L_  = 64;
static constexpr int H_  = 1024;
static constexpr int IN_ = 512;
static constexpr int V_  = 32000;

// GEMM modes
//  0: energy    X[m= b*64+l, k] = k<H ? h[b,k] : enc[(l*B+b)*2H + k-H];      W=W_attn [H,3H];  epilogue: partials
//  1: gi        X[m=b, k] = k<IN ? input_emb[b,k] : weighted[b,k-IN];        W=W_ih  [3H,2560]; C=gi+b_ih
//  2: gh        X[m=b, k] = h[b,k];                                          W=W_hh  [3H,H];    C=gh+b_hh
//  3: logits    X[m=b, k] = k<H ? hnew : (k<3H ? weighted[k-H] : emb[k-3H]); W=W_out [V,3584];  C=logits+b_out

template<int MODE>
__device__ __forceinline__ float loadX(const float* __restrict__ A0,
                                       const float* __restrict__ A1,
                                       const float* __restrict__ A2,
                                       int m, int k) {
    if (MODE == 0) {
        int b = m >> 6, l = m & 63;
        if (k < H_) return A0[b * H_ + k];
        return A1[((size_t)l * B_ + b) * (2 * H_) + (k - H_)];
    } else if (MODE == 1) {
        if (k < IN_) return A0[m * IN_ + k];
        return A1[(size_t)m * (2 * H_) + (k - IN_)];
    } else if (MODE == 2) {
        return A0[m * H_ + k];
    } else {
        if (k < H_) return A0[m * H_ + k];
        if (k < 3 * H_) return A1[(size_t)m * (2 * H_) + (k - H_)];
        return A2[m * IN_ + (k - 3 * H_)];
    }
}

template<int MODE>
__global__ __launch_bounds__(256) void gemm_k(
    const float* __restrict__ A0, const float* __restrict__ A1, const float* __restrict__ A2,
    const float* __restrict__ W,     // [N, K] row-major
    const float* __restrict__ bias,  // [N] (b_attn for MODE 0)
    float* __restrict__ Cout,        // [M, N]  (MODE 0: partials [M, N/64])
    int M, int N, int K,
    const float* __restrict__ vattn) // MODE 0 only
{
    __shared__ float Xs[16][65];
    __shared__ float Ws[16][65];
    __shared__ float red[64][17];

    const int nb = blockIdx.x;
    const int mb = blockIdx.y;
    const int tid = threadIdx.x;
    const int tx = tid & 15, ty = tid >> 4;
    const int m0 = mb * 64, n0 = nb * 64;

    float acc[4][4] = {};

    for (int k0 = 0; k0 < K; k0 += 16) {
        #pragma unroll
        for (int i = 0; i < 4; ++i) {
            int e  = tid + i * 256;
            int mm = e >> 4, kk = e & 15;
            Xs[kk][mm] = loadX<MODE>(A0, A1, A2, m0 + mm, k0 + kk);
            Ws[kk][mm] = W[(size_t)(n0 + mm) * K + (k0 + kk)];
        }
        __syncthreads();
        #pragma unroll
        for (int kk = 0; kk < 16; ++kk) {
            float xr[4], wr[4];
            #pragma unroll
            for (int i = 0; i < 4; ++i) xr[i] = Xs[kk][ty * 4 + i];
            #pragma unroll
            for (int j = 0; j < 4; ++j) wr[j] = Ws[kk][tx * 4 + j];
            #pragma unroll
            for (int i = 0; i < 4; ++i)
                #pragma unroll
                for (int j = 0; j < 4; ++j) acc[i][j] += xr[i] * wr[j];
        }
        __syncthreads();
    }

    if (MODE == 0) {
        // epilogue: partial score over this block's 64 columns
        float part[4];
        #pragma unroll
        for (int i = 0; i < 4; ++i) {
            float s = 0.f;
            #pragma unroll
            for (int j = 0; j < 4; ++j) {
                int n = n0 + tx * 4 + j;
                s += tanhf(acc[i][j] + bias[n]) * vattn[n];
            }
            part[i] = s;
        }
        #pragma unroll
        for (int i = 0; i < 4; ++i) red[ty * 4 + i][tx] = part[i];
        __syncthreads();
        if (tid < 64) {
            float s = 0.f;
            #pragma unroll
            for (int t = 0; t < 16; ++t) s += red[tid][t];
            Cout[(size_t)(m0 + tid) * gridDim.x + nb] = s;
        }
    } else {
        #pragma unroll
        for (int i = 0; i < 4; ++i) {
            int m = m0 + ty * 4 + i;
            #pragma unroll
            for (int j = 0; j < 4; ++j) {
                int n = n0 + tx * 4 + j;
                Cout[(size_t)m * N + n] = acc[i][j] + bias[n];
            }
        }
    }
}

// masked softmax over L=64 (one wave per b); mask is int32 (bool input)
__global__ __launch_bounds__(64) void softmax_k(const float* __restrict__ partials,
                                                const int* __restrict__ mask,
                                                float* __restrict__ attnw)
{
    int b = blockIdx.x;
    int l = threadIdx.x;
    float s = 0.f;
    #pragma unroll
    for (int nb = 0; nb < 16; ++nb) s += partials[(size_t)(b * 64 + l) * 16 + nb];
    if (mask[b * 64 + l] != 0) s = -1e10f;
    float m = s;
    #pragma unroll
    for (int off = 32; off; off >>= 1) m = fmaxf(m, __shfl_xor(m, off));
    float e = expf(s - m);
    float sum = e;
    #pragma unroll
    for (int off = 32; off; off >>= 1) sum += __shfl_xor(sum, off);
    attnw[b * 64 + l] = e / sum;
}

// weighted[b,d] = sum_l attnw[b,l] * enc[l,b,d]
__global__ __launch_bounds__(256) void weighted_k(const float* __restrict__ attnw,
                                                  const float* __restrict__ enc,
                                                  float* __restrict__ weighted)
{
    int b = blockIdx.x;
    int t = threadIdx.x;
    float acc[8] = {};
    for (int l = 0; l < 64; ++l) {
        float w = attnw[b * 64 + l];
        const float* row = enc + ((size_t)l * B_ + b) * (2 * H_);
        #pragma unroll
        for (int i = 0; i < 8; ++i) acc[i] += w * row[t + i * 256];
    }
    #pragma unroll
    for (int i = 0; i < 8; ++i) weighted[(size_t)b * (2 * H_) + t + i * 256] = acc[i];
}

// GRU gates elementwise
__global__ __launch_bounds__(256) void gru_k(const float* __restrict__ gi,
                                             const float* __restrict__ gh,
                                             const float* __restrict__ h,
                                             float* __restrict__ hnew)
{
    int idx = blockIdx.x * 256 + threadIdx.x;  // [0, B*H)
    int b = idx >> 10, j = idx & 1023;
    const float* gib = gi + (size_t)b * (3 * H_);
    const float* ghb = gh + (size_t)b * (3 * H_);
    float r = 1.f / (1.f + expf(-(gib[j] + ghb[j])));
    float z = 1.f / (1.f + expf(-(gib[H_ + j] + ghb[H_ + j])));
    float n = tanhf(gib[2 * H_ + j] + r * ghb[2 * H_ + j]);
    hnew[idx] = (1.f - z) * n + z * h[idx];
}

extern "C" void kernel_launch(void* const* d_in, const int* in_sizes, int n_in,
                              void* d_out, int out_size, void* d_ws, size_t ws_size,
                              hipStream_t stream) {
    const float* input_emb = (const float*)d_in[0];
    const float* hidden    = (const float*)d_in[1];
    const float* enc       = (const float*)d_in[2];
    const int*   mask      = (const int*)d_in[3];
    const float* W_attn = (const float*)d_in[4];
    const float* b_attn = (const float*)d_in[5];
    const float* v_attn = (const float*)d_in[6];
    const float* W_ih   = (const float*)d_in[7];
    const float* W_hh   = (const float*)d_in[8];
    const float* b_ih   = (const float*)d_in[9];
    const float* b_hh   = (const float*)d_in[10];
    const float* W_out  = (const float*)d_in[11];
    const float* b_out  = (const float*)d_in[12];

    float* logits = (float*)d_out;                       // [B, V]
    float* hnew   = logits + (size_t)B_ * V_;            // [B, H]
    float* attnw  = hnew + (size_t)B_ * H_;              // [B, L]

    float* ws       = (float*)d_ws;
    float* partials = ws;                                 // [B*L, 16]   = 262144
    float* weighted = partials + (size_t)B_ * L_ * 16;    // [B, 2H]     = 524288
    float* gi       = weighted + (size_t)B_ * 2 * H_;     // [B, 3H]     = 786432
    float* gh       = gi + (size_t)B_ * 3 * H_;           // [B, 3H]     = 786432

    // 1) energy GEMM + fused tanh/v-dot partial scores
    {
        dim3 grid(H_ / 64, (B_ * L_) / 64);   // (16, 256)
        gemm_k<0><<<grid, 256, 0, stream>>>(hidden, enc, nullptr,
                                            W_attn, b_attn, partials,
                                            B_ * L_, H_, 3 * H_, v_attn);
    }
    // 2) masked softmax -> attn weights (also an output)
    softmax_k<<<B_, 64, 0, stream>>>(partials, mask, attnw);
    // 3) weighted encoder sum
    weighted_k<<<B_, 256, 0, stream>>>(attnw, enc, weighted);
    // 4) gi = [emb, weighted] @ W_ih^T + b_ih
    {
        dim3 grid((3 * H_) / 64, B_ / 64);    // (48, 4)
        gemm_k<1><<<grid, 256, 0, stream>>>(input_emb, weighted, nullptr,
                                            W_ih, b_ih, gi,
                                            B_, 3 * H_, 2 * H_ + IN_, nullptr);
    }
    // 5) gh = h @ W_hh^T + b_hh
    {
        dim3 grid((3 * H_) / 64, B_ / 64);
        gemm_k<2><<<grid, 256, 0, stream>>>(hidden, nullptr, nullptr,
                                            W_hh, b_hh, gh,
                                            B_, 3 * H_, H_, nullptr);
    }
    // 6) GRU gates -> h_new (output)
    gru_k<<<(B_ * H_) / 256, 256, 0, stream>>>(gi, gh, hidden, hnew);
    // 7) logits = [h_new, weighted, emb] @ W_out^T + b_out
    {
        dim3 grid(V_ / 64, B_ / 64);          // (500, 4)
        gemm_k<3><<<grid, 256, 0, stream>>>(hnew, weighted, input_emb,
                                            W_out, b_out, logits,
                                            B_, V_, 3 * H_ + IN_, nullptr);
    }
}

// Round 3
// 1353.244 us; speedup vs baseline: 2.7992x; 2.7992x over previous
//
#include <hip/hip_runtime.h>
#include <cstddef>

static constexpr int B_  = 256;
static constexpr int L_  = 64;
static constexpr int H_  = 1024;
static constexpr int IN_ = 512;
static constexpr int V_  = 32000;

typedef __attribute__((ext_vector_type(8))) short bf8;
typedef __attribute__((ext_vector_type(4))) float f32x4;

__device__ __forceinline__ short f2b(float x) {
    unsigned u = __float_as_uint(x);
    u += 0x7fffu + ((u >> 16) & 1u);
    return (short)(u >> 16);
}

// X loaders. MODE 0: h[m,1024]. MODE 1: [emb(512), weighted(2048)]. MODE 2: [hnew(1024), weighted(2048), emb(512)]
template<int MODE>
__device__ __forceinline__ float4 loadX4(const float* __restrict__ A0,
                                         const float* __restrict__ A1,
                                         const float* __restrict__ A2,
                                         int m, int k) {
    if constexpr (MODE == 0) {
        return *(const float4*)(A0 + (size_t)m * 1024 + k);
    } else if constexpr (MODE == 1) {
        if (k < 512) return *(const float4*)(A0 + (size_t)m * 512 + k);
        return *(const float4*)(A1 + (size_t)m * 2048 + (k - 512));
    } else {
        if (k < 1024) return *(const float4*)(A0 + (size_t)m * 1024 + k);
        if (k < 3072) return *(const float4*)(A1 + (size_t)m * 2048 + (k - 1024));
        return *(const float4*)(A2 + (size_t)m * 512 + (k - 3072));
    }
}

// C[256, N] = X[256, K] * W[N, K]^T (+bias). BM=256 (=M), BN=128, BK=32.
// grid.x = N/128 blocks, 512 threads (8 waves: 4 row x 2 col), wave tile 64x64.
template<int MODE>
__global__ __launch_bounds__(512) void gemm_mfma(
    const float* __restrict__ A0, const float* __restrict__ A1, const float* __restrict__ A2,
    const float* __restrict__ W, int ldw,
    const float* __restrict__ bias,
    float* __restrict__ out, int Nout, int K)
{
    __shared__ short Xs[256 * 40];
    __shared__ short Ws[128 * 40];

    const int tid = threadIdx.x;
    const int n0 = blockIdx.x * 128;
    const int wid = tid >> 6, lane = tid & 63;
    const int wrow = wid >> 1, wcol = wid & 1;
    const int ln15 = lane & 15, kq = lane >> 4;

    f32x4 acc[4][4];
    #pragma unroll
    for (int i = 0; i < 4; ++i)
        #pragma unroll
        for (int j = 0; j < 4; ++j) acc[i][j] = {0.f, 0.f, 0.f, 0.f};

    const int xrow = tid >> 1, xkh = (tid & 1) * 16;
    const int wrow_s = tid >> 2, wkh = (tid & 3) * 8;

    for (int k0 = 0; k0 < K; k0 += 32) {
        // stage X: 256x32 f32 -> bf16, 16 floats/thread
        {
            float v[16];
            #pragma unroll
            for (int c = 0; c < 4; ++c) {
                float4 f = loadX4<MODE>(A0, A1, A2, xrow, k0 + xkh + c * 4);
                v[c*4+0] = f.x; v[c*4+1] = f.y; v[c*4+2] = f.z; v[c*4+3] = f.w;
            }
            bf8 s0, s1;
            #pragma unroll
            for (int c = 0; c < 8; ++c) { s0[c] = f2b(v[c]); s1[c] = f2b(v[8 + c]); }
            *(bf8*)&Xs[xrow * 40 + xkh] = s0;
            *(bf8*)&Xs[xrow * 40 + xkh + 8] = s1;
        }
        // stage W: 128x32 f32 -> bf16, 8 floats/thread
        {
            const float* wp = W + (size_t)(n0 + wrow_s) * ldw + k0 + wkh;
            float4 f0 = *(const float4*)wp;
            float4 f1 = *(const float4*)(wp + 4);
            bf8 s;
            s[0]=f2b(f0.x); s[1]=f2b(f0.y); s[2]=f2b(f0.z); s[3]=f2b(f0.w);
            s[4]=f2b(f1.x); s[5]=f2b(f1.y); s[6]=f2b(f1.z); s[7]=f2b(f1.w);
            *(bf8*)&Ws[wrow_s * 40 + wkh] = s;
        }
        __syncthreads();

        bf8 af[4], bfr[4];
        #pragma unroll
        for (int i = 0; i < 4; ++i)
            af[i] = *(const bf8*)&Xs[(wrow * 64 + i * 16 + ln15) * 40 + kq * 8];
        #pragma unroll
        for (int j = 0; j < 4; ++j)
            bfr[j] = *(const bf8*)&Ws[(wcol * 64 + j * 16 + ln15) * 40 + kq * 8];
        #pragma unroll
        for (int i = 0; i < 4; ++i)
            #pragma unroll
            for (int j = 0; j < 4; ++j)
                acc[i][j] = __builtin_amdgcn_mfma_f32_16x16x32_bf16(af[i], bfr[j], acc[i][j], 0, 0, 0);
        __syncthreads();
    }

    // epilogue: C/D map col=lane&15, row=(lane>>4)*4+r
    #pragma unroll
    for (int i = 0; i < 4; ++i) {
        #pragma unroll
        for (int j = 0; j < 4; ++j) {
            int col = n0 + wcol * 64 + j * 16 + ln15;
            float bv = bias ? bias[col] : 0.f;
            #pragma unroll
            for (int r = 0; r < 4; ++r) {
                int row = wrow * 64 + i * 16 + kq * 4 + r;
                out[(size_t)row * Nout + col] = acc[i][j][r] + bv;
            }
        }
    }
}

// E2 = enc * W2^T fused with tanh(E1+E2+b_attn)*v_attn and column-reduce to partials.
// BM=128 (m rows), BN=256 (h cols), BK=32. grid (4 nb, 128 mb). 8 waves: 2 row x 4 col, wave 64x64.
__global__ __launch_bounds__(512) void energy_mfma(
    const float* __restrict__ enc,
    const float* __restrict__ W_attn,   // [1024, 3072]; use cols 1024..3071
    const float* __restrict__ E1,       // [256, 1024]
    const float* __restrict__ b_attn,
    const float* __restrict__ v_attn,
    float* __restrict__ partials)       // [16384, 16]
{
    __shared__ short Xs[128 * 40];
    __shared__ short Ws[256 * 40];

    const int tid = threadIdx.x;
    const int nb = blockIdx.x;
    const int n0 = nb * 256;
    const int m0 = blockIdx.y * 128;
    const int wid = tid >> 6, lane = tid & 63;
    const int wrow = wid >> 2, wcol = wid & 3;
    const int ln15 = lane & 15, kq = lane >> 4;

    f32x4 acc[4][4];
    #pragma unroll
    for (int i = 0; i < 4; ++i)
        #pragma unroll
        for (int j = 0; j < 4; ++j) acc[i][j] = {0.f, 0.f, 0.f, 0.f};

    // X staging map: 128 rows x 32, 8 floats/thread
    const int xrow = tid >> 2, xkh = (tid & 3) * 8;
    const int xb = (m0 + xrow) >> 6, xl = (m0 + xrow) & 63;
    const float* xbase = enc + ((size_t)xl * B_ + xb) * 2048;
    // W staging map: 256 rows x 32, 16 floats/thread
    const int wr = tid >> 1, wkh = (tid & 1) * 16;
    const float* wbase = W_attn + (size_t)(n0 + wr) * 3072 + 1024;

    for (int k0 = 0; k0 < 2048; k0 += 32) {
        {
            float4 f0 = *(const float4*)(xbase + k0 + xkh);
            float4 f1 = *(const float4*)(xbase + k0 + xkh + 4);
            bf8 s;
            s[0]=f2b(f0.x); s[1]=f2b(f0.y); s[2]=f2b(f0.z); s[3]=f2b(f0.w);
            s[4]=f2b(f1.x); s[5]=f2b(f1.y); s[6]=f2b(f1.z); s[7]=f2b(f1.w);
            *(bf8*)&Xs[xrow * 40 + xkh] = s;
        }
        {
            float v[16];
            #pragma unroll
            for (int c = 0; c < 4; ++c) {
                float4 f = *(const float4*)(wbase + k0 + wkh + c * 4);
                v[c*4+0] = f.x; v[c*4+1] = f.y; v[c*4+2] = f.z; v[c*4+3] = f.w;
            }
            bf8 s0, s1;
            #pragma unroll
            for (int c = 0; c < 8; ++c) { s0[c] = f2b(v[c]); s1[c] = f2b(v[8 + c]); }
            *(bf8*)&Ws[wr * 40 + wkh] = s0;
            *(bf8*)&Ws[wr * 40 + wkh + 8] = s1;
        }
        __syncthreads();

        bf8 af[4], bfr[4];
        #pragma unroll
        for (int i = 0; i < 4; ++i)
            af[i] = *(const bf8*)&Xs[(wrow * 64 + i * 16 + ln15) * 40 + kq * 8];
        #pragma unroll
        for (int j = 0; j < 4; ++j)
            bfr[j] = *(const bf8*)&Ws[(wcol * 64 + j * 16 + ln15) * 40 + kq * 8];
        #pragma unroll
        for (int i = 0; i < 4; ++i)
            #pragma unroll
            for (int j = 0; j < 4; ++j)
                acc[i][j] = __builtin_amdgcn_mfma_f32_16x16x32_bf16(af[i], bfr[j], acc[i][j], 0, 0, 0);
        __syncthreads();
    }

    // epilogue: tanh(E2 + E1 + b_attn) * v_attn, reduce over this wave's 64 cols
    float rs[4][4];
    #pragma unroll
    for (int i = 0; i < 4; ++i)
        #pragma unroll
        for (int r = 0; r < 4; ++r) rs[i][r] = 0.f;

    #pragma unroll
    for (int i = 0; i < 4; ++i) {
        #pragma unroll
        for (int j = 0; j < 4; ++j) {
            int col = n0 + wcol * 64 + j * 16 + ln15;
            float bv = b_attn[col], vv = v_attn[col];
            #pragma unroll
            for (int r = 0; r < 4; ++r) {
                int m = m0 + wrow * 64 + i * 16 + kq * 4 + r;
                float e = tanhf(acc[i][j][r] + E1[(size_t)(m >> 6) * 1024 + col] + bv);
                rs[i][r] += e * vv;
            }
        }
    }
    #pragma unroll
    for (int i = 0; i < 4; ++i)
        #pragma unroll
        for (int r = 0; r < 4; ++r) {
            float s = rs[i][r];
            #pragma unroll
            for (int off = 1; off < 16; off <<= 1) s += __shfl_xor(s, off);
            rs[i][r] = s;
        }
    if (ln15 == 0) {
        #pragma unroll
        for (int i = 0; i < 4; ++i)
            #pragma unroll
            for (int r = 0; r < 4; ++r) {
                int m = m0 + wrow * 64 + i * 16 + kq * 4 + r;
                partials[(size_t)m * 16 + nb * 4 + wcol] = rs[i][r];
            }
    }
}

// masked softmax over L=64 (one wave per b); mask int32
__global__ __launch_bounds__(64) void softmax_k(const float* __restrict__ partials,
                                                const int* __restrict__ mask,
                                                float* __restrict__ attnw)
{
    int b = blockIdx.x;
    int l = threadIdx.x;
    float s = 0.f;
    #pragma unroll
    for (int nb = 0; nb < 16; ++nb) s += partials[(size_t)(b * 64 + l) * 16 + nb];
    if (mask[b * 64 + l] != 0) s = -1e10f;
    float m = s;
    #pragma unroll
    for (int off = 32; off; off >>= 1) m = fmaxf(m, __shfl_xor(m, off));
    float e = expf(s - m);
    float sum = e;
    #pragma unroll
    for (int off = 32; off; off >>= 1) sum += __shfl_xor(sum, off);
    attnw[b * 64 + l] = e / sum;
}

// weighted[b,d] = sum_l attnw[b,l] * enc[l,b,d]
__global__ __launch_bounds__(256) void weighted_k(const float* __restrict__ attnw,
                                                  const float* __restrict__ enc,
                                                  float* __restrict__ weighted)
{
    int b = blockIdx.x;
    int t = threadIdx.x;
    float acc[8] = {};
    for (int l = 0; l < 64; ++l) {
        float w = attnw[b * 64 + l];
        const float* row = enc + ((size_t)l * B_ + b) * (2 * H_);
        #pragma unroll
        for (int i = 0; i < 8; ++i) acc[i] += w * row[t + i * 256];
    }
    #pragma unroll
    for (int i = 0; i < 8; ++i) weighted[(size_t)b * (2 * H_) + t + i * 256] = acc[i];
}

// GRU gates elementwise
__global__ __launch_bounds__(256) void gru_k(const float* __restrict__ gi,
                                             const float* __restrict__ gh,
                                             const float* __restrict__ h,
                                             float* __restrict__ hnew)
{
    int idx = blockIdx.x * 256 + threadIdx.x;
    int b = idx >> 10, j = idx & 1023;
    const float* gib = gi + (size_t)b * (3 * H_);
    const float* ghb = gh + (size_t)b * (3 * H_);
    float r = 1.f / (1.f + expf(-(gib[j] + ghb[j])));
    float z = 1.f / (1.f + expf(-(gib[H_ + j] + ghb[H_ + j])));
    float n = tanhf(gib[2 * H_ + j] + r * ghb[2 * H_ + j]);
    hnew[idx] = (1.f - z) * n + z * h[idx];
}

extern "C" void kernel_launch(void* const* d_in, const int* in_sizes, int n_in,
                              void* d_out, int out_size, void* d_ws, size_t ws_size,
                              hipStream_t stream) {
    const float* input_emb = (const float*)d_in[0];
    const float* hidden    = (const float*)d_in[1];
    const float* enc       = (const float*)d_in[2];
    const int*   mask      = (const int*)d_in[3];
    const float* W_attn = (const float*)d_in[4];
    const float* b_attn = (const float*)d_in[5];
    const float* v_attn = (const float*)d_in[6];
    const float* W_ih   = (const float*)d_in[7];
    const float* W_hh   = (const float*)d_in[8];
    const float* b_ih   = (const float*)d_in[9];
    const float* b_hh   = (const float*)d_in[10];
    const float* W_out  = (const float*)d_in[11];
    const float* b_out  = (const float*)d_in[12];

    float* logits = (float*)d_out;
    float* hnew   = logits + (size_t)B_ * V_;
    float* attnw  = hnew + (size_t)B_ * H_;

    float* ws       = (float*)d_ws;
    float* partials = ws;                                  // [16384,16] 1 MB
    float* weighted = partials + (size_t)B_ * L_ * 16;     // [256,2048] 2 MB
    float* gi       = weighted + (size_t)B_ * 2 * H_;      // [256,3072] 3 MB
    float* gh       = gi + (size_t)B_ * 3 * H_;            // [256,3072] 3 MB
    float* E1       = gh + (size_t)B_ * 3 * H_;            // [256,1024] 1 MB

    // E1 = h @ W_attn[:, :1024]^T  (no bias)
    gemm_mfma<0><<<8, 512, 0, stream>>>(hidden, nullptr, nullptr,
                                        W_attn, 3072, nullptr, E1, 1024, 1024);
    // E2 + fused tanh/v-dot -> partials
    {
        dim3 grid(4, 128);
        energy_mfma<<<grid, 512, 0, stream>>>(enc, W_attn, E1, b_attn, v_attn, partials);
    }
    softmax_k<<<B_, 64, 0, stream>>>(partials, mask, attnw);
    weighted_k<<<B_, 256, 0, stream>>>(attnw, enc, weighted);
    // gi = [emb, weighted] @ W_ih^T + b_ih
    gemm_mfma<1><<<24, 512, 0, stream>>>(input_emb, weighted, nullptr,
                                         W_ih, 2560, b_ih, gi, 3072, 2560);
    // gh = h @ W_hh^T + b_hh
    gemm_mfma<0><<<24, 512, 0, stream>>>(hidden, nullptr, nullptr,
                                         W_hh, 1024, b_hh, gh, 3072, 1024);
    gru_k<<<(B_ * H_) / 256, 256, 0, stream>>>(gi, gh, hidden, hnew);
    // logits = [hnew, weighted, emb] @ W_out^T + b_out
    gemm_mfma<2><<<250, 512, 0, stream>>>(hnew, weighted, input_emb,
                                          W_out, 3584, b_out, logits, 32000, 3584);
}

// Round 4
// 550.212 us; speedup vs baseline: 6.8845x; 2.4595x over previous
//
#include <hip/hip_runtime.h>
#include <cstddef>

static constexpr int B_  = 256;
static constexpr int L_  = 64;
static constexpr int H_  = 1024;
static constexpr int IN_ = 512;
static constexpr int V_  = 32000;

typedef __attribute__((ext_vector_type(8))) short bf8;
typedef __attribute__((ext_vector_type(4))) short s4;
typedef __attribute__((ext_vector_type(4))) float f32x4;

__device__ __forceinline__ short f2b(float x) {
    unsigned u = __float_as_uint(x);
    u += 0x7fffu + ((u >> 16) & 1u);
    return (short)(u >> 16);
}
__device__ __forceinline__ bf8 pack8(const float4& a, const float4& b) {
    bf8 r;
    r[0]=f2b(a.x); r[1]=f2b(a.y); r[2]=f2b(a.z); r[3]=f2b(a.w);
    r[4]=f2b(b.x); r[5]=f2b(b.y); r[6]=f2b(b.z); r[7]=f2b(b.w);
    return r;
}

// ---------------- conversion kernels ----------------
// h -> h_bf ; emb -> xgi_bf[:,0:512] and xlo_bf[:,3072:3584]
__global__ __launch_bounds__(256) void conv_static(
    const float* __restrict__ h, const float* __restrict__ emb,
    short* __restrict__ h_bf, short* __restrict__ xgi, short* __restrict__ xlo)
{
    int u = blockIdx.x * 256 + threadIdx.x;          // float4 units
    if (u < 65536) {                                  // h: 256*1024/4
        float4 f = *(const float4*)(h + (size_t)u * 4);
        s4 s; s[0]=f2b(f.x); s[1]=f2b(f.y); s[2]=f2b(f.z); s[3]=f2b(f.w);
        *(s4*)(h_bf + (size_t)u * 4) = s;
    } else {                                          // emb: 256*512/4 = 32768
        int e = u - 65536;
        int m = e >> 7, c4 = (e & 127) * 4;
        float4 f = *(const float4*)(emb + (size_t)m * 512 + c4);
        s4 s; s[0]=f2b(f.x); s[1]=f2b(f.y); s[2]=f2b(f.z); s[3]=f2b(f.w);
        *(s4*)(xgi + (size_t)m * 2560 + c4) = s;
        *(s4*)(xlo + (size_t)m * 3584 + 3072 + c4) = s;
    }
}

// W_attn[:, 1024:3072] -> Wattn2_bf [1024][2048]
__global__ __launch_bounds__(256) void conv_wattn2(
    const float* __restrict__ W_attn, short* __restrict__ Wb)
{
    int o = blockIdx.x * 256 + threadIdx.x;           // float4 units, 524288
    int r = o >> 9, c4 = (o & 511) * 4;
    float4 f = *(const float4*)(W_attn + (size_t)r * 3072 + 1024 + c4);
    s4 s; s[0]=f2b(f.x); s[1]=f2b(f.y); s[2]=f2b(f.z); s[3]=f2b(f.w);
    *(s4*)(Wb + (size_t)r * 2048 + c4) = s;
}

// ---------------- main GEMM: C[256,N] = Xb[256,K](bf16) * W[N,K](f32)^T ----------------
// BM=256, BN=128, BK=64. 512 thr = 8 waves (4 row x 2 col), wave tile 64x64.
// MODE 0: plain (W0,bias,out0).  MODE 1: combo E1(n<1024, no bias) + gh(n>=1024, b_hh).
template<int MODE>
__global__ __launch_bounds__(512, 2) void gemm2(
    const short* __restrict__ Xb, int ldx, int K,
    const float* __restrict__ W0, int ldw0,
    const float* __restrict__ W1,
    const float* __restrict__ bias,
    float* __restrict__ out0, int ldo0,
    float* __restrict__ out1)
{
    __shared__ short Xs[256 * 64];
    __shared__ short Ws[128 * 64];

    const int tid = threadIdx.x;
    const int n0 = blockIdx.x * 128;
    const int wid = tid >> 6, lane = tid & 63;
    const int wrow = wid >> 1, wcol = wid & 1;
    const int ln15 = lane & 15, kq = lane >> 4;

    const float* Wsrc; int ldw;
    if (MODE == 1) {
        if (n0 < 1024) { Wsrc = W0 + (size_t)n0 * ldw0; ldw = ldw0; }
        else           { Wsrc = W1 + (size_t)(n0 - 1024) * 1024; ldw = 1024; }
    } else { Wsrc = W0 + (size_t)n0 * ldw0; ldw = ldw0; }

    // staging maps (constant per thread)
    int xrow[4], xdst[4]; const short* xsrc[4];
    #pragma unroll
    for (int c = 0; c < 4; ++c) {
        int o = c * 512 + tid;            // 2048 16B chunks
        int row = o >> 3, cb = o & 7;
        xrow[c] = row;
        xsrc[c] = Xb + (size_t)row * ldx + cb * 8;
        xdst[c] = row * 64 + ((cb * 8) ^ ((row & 7) << 3));
    }
    int wdst[2]; const float* wsrcp[2];
    #pragma unroll
    for (int g = 0; g < 2; ++g) {
        int o = g * 512 + tid;            // 1024 groups of 8 f32
        int row = o >> 3, gb = o & 7;
        wsrcp[g] = Wsrc + (size_t)row * ldw + gb * 8;
        wdst[g] = row * 64 + ((gb * 8) ^ ((row & 7) << 3));
    }
    // fragment read offsets
    int aoff[2][4], boff[2][4];
    #pragma unroll
    for (int ks = 0; ks < 2; ++ks) {
        #pragma unroll
        for (int i = 0; i < 4; ++i) {
            int ar = wrow * 64 + i * 16 + ln15;
            aoff[ks][i] = ar * 64 + ((ks * 32 + kq * 8) ^ ((ar & 7) << 3));
            int br = wcol * 64 + i * 16 + ln15;
            boff[ks][i] = br * 64 + ((ks * 32 + kq * 8) ^ ((br & 7) << 3));
        }
    }

    f32x4 acc[4][4];
    #pragma unroll
    for (int i = 0; i < 4; ++i)
        #pragma unroll
        for (int j = 0; j < 4; ++j) acc[i][j] = {0.f, 0.f, 0.f, 0.f};

    bf8 xA[4], xB[4];
    float4 wA[4], wB[4];

    const int NT = K >> 6;

    // prologue: load tile 0 -> set A
    #pragma unroll
    for (int c = 0; c < 4; ++c) xA[c] = *(const bf8*)(xsrc[c]);
    #pragma unroll
    for (int g = 0; g < 2; ++g) {
        wA[2*g]   = *(const float4*)(wsrcp[g]);
        wA[2*g+1] = *(const float4*)(wsrcp[g] + 4);
    }

    for (int t = 0; t < NT; t += 2) {
        // ---- half 1: store A, prefetch B(t+1), compute ----
        __syncthreads();
        #pragma unroll
        for (int c = 0; c < 4; ++c) *(bf8*)&Xs[xdst[c]] = xA[c];
        #pragma unroll
        for (int g = 0; g < 2; ++g) *(bf8*)&Ws[wdst[g]] = pack8(wA[2*g], wA[2*g+1]);
        if (t + 1 < NT) {
            int k0 = (t + 1) << 6;
            #pragma unroll
            for (int c = 0; c < 4; ++c) xB[c] = *(const bf8*)(xsrc[c] + k0);
            #pragma unroll
            for (int g = 0; g < 2; ++g) {
                wB[2*g]   = *(const float4*)(wsrcp[g] + k0);
                wB[2*g+1] = *(const float4*)(wsrcp[g] + k0 + 4);
            }
        }
        __syncthreads();
        #pragma unroll
        for (int ks = 0; ks < 2; ++ks) {
            bf8 a[4], b[4];
            #pragma unroll
            for (int i = 0; i < 4; ++i) a[i] = *(const bf8*)&Xs[aoff[ks][i]];
            #pragma unroll
            for (int j = 0; j < 4; ++j) b[j] = *(const bf8*)&Ws[boff[ks][j]];
            #pragma unroll
            for (int i = 0; i < 4; ++i)
                #pragma unroll
                for (int j = 0; j < 4; ++j)
                    acc[i][j] = __builtin_amdgcn_mfma_f32_16x16x32_bf16(a[i], b[j], acc[i][j], 0, 0, 0);
        }
        if (t + 1 >= NT) break;
        // ---- half 2: store B, prefetch A(t+2), compute ----
        __syncthreads();
        #pragma unroll
        for (int c = 0; c < 4; ++c) *(bf8*)&Xs[xdst[c]] = xB[c];
        #pragma unroll
        for (int g = 0; g < 2; ++g) *(bf8*)&Ws[wdst[g]] = pack8(wB[2*g], wB[2*g+1]);
        if (t + 2 < NT) {
            int k0 = (t + 2) << 6;
            #pragma unroll
            for (int c = 0; c < 4; ++c) xA[c] = *(const bf8*)(xsrc[c] + k0);
            #pragma unroll
            for (int g = 0; g < 2; ++g) {
                wA[2*g]   = *(const float4*)(wsrcp[g] + k0);
                wA[2*g+1] = *(const float4*)(wsrcp[g] + k0 + 4);
            }
        }
        __syncthreads();
        #pragma unroll
        for (int ks = 0; ks < 2; ++ks) {
            bf8 a[4], b[4];
            #pragma unroll
            for (int i = 0; i < 4; ++i) a[i] = *(const bf8*)&Xs[aoff[ks][i]];
            #pragma unroll
            for (int j = 0; j < 4; ++j) b[j] = *(const bf8*)&Ws[boff[ks][j]];
            #pragma unroll
            for (int i = 0; i < 4; ++i)
                #pragma unroll
                for (int j = 0; j < 4; ++j)
                    acc[i][j] = __builtin_amdgcn_mfma_f32_16x16x32_bf16(a[i], b[j], acc[i][j], 0, 0, 0);
        }
    }

    // epilogue: C/D map col=lane&15, row=(lane>>4)*4+r
    #pragma unroll
    for (int i = 0; i < 4; ++i) {
        #pragma unroll
        for (int j = 0; j < 4; ++j) {
            int col = n0 + wcol * 64 + j * 16 + ln15;
            #pragma unroll
            for (int r = 0; r < 4; ++r) {
                int row = wrow * 64 + i * 16 + kq * 4 + r;
                float v = acc[i][j][r];
                if (MODE == 1) {
                    if (n0 < 1024) out0[(size_t)row * ldo0 + col] = v;
                    else           out1[(size_t)row * 3072 + (col - 1024)] = v + bias[col - 1024];
                } else {
                    out0[(size_t)row * ldo0 + col] = v + (bias ? bias[col] : 0.f);
                }
            }
        }
    }
}

// ---------------- energy: E2 = enc(f32->bf16) * Wattn2_bf^T, fused tanh/v epilogue ----------------
// BM=128, BN=256, BK=64. grid (4 nb, 128 mb). 512 thr = 8 waves (2 row x 4 col), wave 64x64.
__global__ __launch_bounds__(512, 2) void energy2(
    const float* __restrict__ enc,
    const short* __restrict__ Wb,       // [1024][2048] bf16
    const float* __restrict__ E1,       // [256][1024]
    const float* __restrict__ b_attn,
    const float* __restrict__ v_attn,
    float* __restrict__ partials)       // [16384][16]
{
    __shared__ short Xs[128 * 64];
    __shared__ short Ws[256 * 64];

    const int tid = threadIdx.x;
    const int nb = blockIdx.x, n0 = nb * 256;
    const int m0 = blockIdx.y * 128;
    const int wid = tid >> 6, lane = tid & 63;
    const int wrow = wid >> 2, wcol = wid & 3;
    const int ln15 = lane & 15, kq = lane >> 4;

    // X staging: 2 groups of 8 f32
    int xdst[2]; const float* xsrc[2];
    #pragma unroll
    for (int g = 0; g < 2; ++g) {
        int o = g * 512 + tid;
        int row = o >> 3, gb = o & 7;
        int m = m0 + row, b = m >> 6, l = m & 63;
        xsrc[g] = enc + ((size_t)l * B_ + b) * 2048 + gb * 8;
        xdst[g] = row * 64 + ((gb * 8) ^ ((row & 7) << 3));
    }
    // W staging: 4 chunks of 8 bf16
    int wdst[4]; const short* wsrcp[4];
    #pragma unroll
    for (int c = 0; c < 4; ++c) {
        int o = c * 512 + tid;
        int row = o >> 3, cb = o & 7;
        wsrcp[c] = Wb + (size_t)(n0 + row) * 2048 + cb * 8;
        wdst[c] = row * 64 + ((cb * 8) ^ ((row & 7) << 3));
    }
    int aoff[2][4], boff[2][4];
    #pragma unroll
    for (int ks = 0; ks < 2; ++ks) {
        #pragma unroll
        for (int i = 0; i < 4; ++i) {
            int ar = wrow * 64 + i * 16 + ln15;
            aoff[ks][i] = ar * 64 + ((ks * 32 + kq * 8) ^ ((ar & 7) << 3));
            int br = wcol * 64 + i * 16 + ln15;
            boff[ks][i] = br * 64 + ((ks * 32 + kq * 8) ^ ((br & 7) << 3));
        }
    }

    f32x4 acc[4][4];
    #pragma unroll
    for (int i = 0; i < 4; ++i)
        #pragma unroll
        for (int j = 0; j < 4; ++j) acc[i][j] = {0.f, 0.f, 0.f, 0.f};

    float4 xA[4], xB[4];
    bf8 wA[4], wB[4];

    const int NT = 32;  // K = 2048

    #pragma unroll
    for (int g = 0; g < 2; ++g) {
        xA[2*g]   = *(const float4*)(xsrc[g]);
        xA[2*g+1] = *(const float4*)(xsrc[g] + 4);
    }
    #pragma unroll
    for (int c = 0; c < 4; ++c) wA[c] = *(const bf8*)(wsrcp[c]);

    for (int t = 0; t < NT; t += 2) {
        __syncthreads();
        #pragma unroll
        for (int g = 0; g < 2; ++g) *(bf8*)&Xs[xdst[g]] = pack8(xA[2*g], xA[2*g+1]);
        #pragma unroll
        for (int c = 0; c < 4; ++c) *(bf8*)&Ws[wdst[c]] = wA[c];
        {
            int k0 = (t + 1) << 6;
            #pragma unroll
            for (int g = 0; g < 2; ++g) {
                xB[2*g]   = *(const float4*)(xsrc[g] + k0);
                xB[2*g+1] = *(const float4*)(xsrc[g] + k0 + 4);
            }
            #pragma unroll
            for (int c = 0; c < 4; ++c) wB[c] = *(const bf8*)(wsrcp[c] + k0);
        }
        __syncthreads();
        #pragma unroll
        for (int ks = 0; ks < 2; ++ks) {
            bf8 a[4], b[4];
            #pragma unroll
            for (int i = 0; i < 4; ++i) a[i] = *(const bf8*)&Xs[aoff[ks][i]];
            #pragma unroll
            for (int j = 0; j < 4; ++j) b[j] = *(const bf8*)&Ws[boff[ks][j]];
            #pragma unroll
            for (int i = 0; i < 4; ++i)
                #pragma unroll
                for (int j = 0; j < 4; ++j)
                    acc[i][j] = __builtin_amdgcn_mfma_f32_16x16x32_bf16(a[i], b[j], acc[i][j], 0, 0, 0);
        }
        __syncthreads();
        #pragma unroll
        for (int g = 0; g < 2; ++g) *(bf8*)&Xs[xdst[g]] = pack8(xB[2*g], xB[2*g+1]);
        #pragma unroll
        for (int c = 0; c < 4; ++c) *(bf8*)&Ws[wdst[c]] = wB[c];
        if (t + 2 < NT) {
            int k0 = (t + 2) << 6;
            #pragma unroll
            for (int g = 0; g < 2; ++g) {
                xA[2*g]   = *(const float4*)(xsrc[g] + k0);
                xA[2*g+1] = *(const float4*)(xsrc[g] + k0 + 4);
            }
            #pragma unroll
            for (int c = 0; c < 4; ++c) wA[c] = *(const bf8*)(wsrcp[c] + k0);
        }
        __syncthreads();
        #pragma unroll
        for (int ks = 0; ks < 2; ++ks) {
            bf8 a[4], b[4];
            #pragma unroll
            for (int i = 0; i < 4; ++i) a[i] = *(const bf8*)&Xs[aoff[ks][i]];
            #pragma unroll
            for (int j = 0; j < 4; ++j) b[j] = *(const bf8*)&Ws[boff[ks][j]];
            #pragma unroll
            for (int i = 0; i < 4; ++i)
                #pragma unroll
                for (int j = 0; j < 4; ++j)
                    acc[i][j] = __builtin_amdgcn_mfma_f32_16x16x32_bf16(a[i], b[j], acc[i][j], 0, 0, 0);
        }
    }

    // epilogue: tanh(E2 + E1 + b_attn) * v_attn, reduce over wave's 64 cols
    float rs[4][4];
    #pragma unroll
    for (int i = 0; i < 4; ++i)
        #pragma unroll
        for (int r = 0; r < 4; ++r) rs[i][r] = 0.f;

    #pragma unroll
    for (int i = 0; i < 4; ++i) {
        #pragma unroll
        for (int j = 0; j < 4; ++j) {
            int col = n0 + wcol * 64 + j * 16 + ln15;
            float bv = b_attn[col], vv = v_attn[col];
            #pragma unroll
            for (int r = 0; r < 4; ++r) {
                int m = m0 + wrow * 64 + i * 16 + kq * 4 + r;
                float e = tanhf(acc[i][j][r] + E1[(size_t)(m >> 6) * 1024 + col] + bv);
                rs[i][r] += e * vv;
            }
        }
    }
    #pragma unroll
    for (int i = 0; i < 4; ++i)
        #pragma unroll
        for (int r = 0; r < 4; ++r) {
            float s = rs[i][r];
            #pragma unroll
            for (int off = 1; off < 16; off <<= 1) s += __shfl_xor(s, off);
            rs[i][r] = s;
        }
    if (ln15 == 0) {
        #pragma unroll
        for (int i = 0; i < 4; ++i)
            #pragma unroll
            for (int r = 0; r < 4; ++r) {
                int m = m0 + wrow * 64 + i * 16 + kq * 4 + r;
                partials[(size_t)m * 16 + nb * 4 + wcol] = rs[i][r];
            }
    }
}

// masked softmax over L=64
__global__ __launch_bounds__(64) void softmax_k(const float* __restrict__ partials,
                                                const int* __restrict__ mask,
                                                float* __restrict__ attnw)
{
    int b = blockIdx.x;
    int l = threadIdx.x;
    float s = 0.f;
    #pragma unroll
    for (int nb = 0; nb < 16; ++nb) s += partials[(size_t)(b * 64 + l) * 16 + nb];
    if (mask[b * 64 + l] != 0) s = -1e10f;
    float m = s;
    #pragma unroll
    for (int off = 32; off; off >>= 1) m = fmaxf(m, __shfl_xor(m, off));
    float e = expf(s - m);
    float sum = e;
    #pragma unroll
    for (int off = 32; off; off >>= 1) sum += __shfl_xor(sum, off);
    attnw[b * 64 + l] = e / sum;
}

// weighted -> bf16 into xgi_bf[:,512:2560] and xlo_bf[:,1024:3072]
__global__ __launch_bounds__(256) void weighted2(const float* __restrict__ attnw,
                                                 const float* __restrict__ enc,
                                                 short* __restrict__ xgi,
                                                 short* __restrict__ xlo)
{
    int b = blockIdx.x;
    int t = threadIdx.x;
    float acc[8] = {};
    for (int l = 0; l < 64; ++l) {
        float w = attnw[b * 64 + l];
        const float* row = enc + ((size_t)l * B_ + b) * 2048;
        #pragma unroll
        for (int i = 0; i < 8; ++i) acc[i] += w * row[t + i * 256];
    }
    #pragma unroll
    for (int i = 0; i < 8; ++i) {
        short s = f2b(acc[i]);
        int d = t + i * 256;
        xgi[(size_t)b * 2560 + 512 + d] = s;
        xlo[(size_t)b * 3584 + 1024 + d] = s;
    }
}

// GRU gates; writes hnew (f32 output) and xlo_bf[:,0:1024]
__global__ __launch_bounds__(256) void gru2(const float* __restrict__ gi,
                                            const float* __restrict__ gh,
                                            const float* __restrict__ h,
                                            float* __restrict__ hnew,
                                            short* __restrict__ xlo)
{
    int idx = blockIdx.x * 256 + threadIdx.x;
    int b = idx >> 10, j = idx & 1023;
    const float* gib = gi + (size_t)b * 3072;
    const float* ghb = gh + (size_t)b * 3072;
    float r = 1.f / (1.f + expf(-(gib[j] + ghb[j])));
    float z = 1.f / (1.f + expf(-(gib[1024 + j] + ghb[1024 + j])));
    float n = tanhf(gib[2048 + j] + r * ghb[2048 + j]);
    float hv = (1.f - z) * n + z * h[idx];
    hnew[idx] = hv;
    xlo[(size_t)b * 3584 + j] = f2b(hv);
}

extern "C" void kernel_launch(void* const* d_in, const int* in_sizes, int n_in,
                              void* d_out, int out_size, void* d_ws, size_t ws_size,
                              hipStream_t stream) {
    const float* input_emb = (const float*)d_in[0];
    const float* hidden    = (const float*)d_in[1];
    const float* enc       = (const float*)d_in[2];
    const int*   mask      = (const int*)d_in[3];
    const float* W_attn = (const float*)d_in[4];
    const float* b_attn = (const float*)d_in[5];
    const float* v_attn = (const float*)d_in[6];
    const float* W_ih   = (const float*)d_in[7];
    const float* W_hh   = (const float*)d_in[8];
    const float* b_ih   = (const float*)d_in[9];
    const float* b_hh   = (const float*)d_in[10];
    const float* W_out  = (const float*)d_in[11];
    const float* b_out  = (const float*)d_in[12];

    float* logits = (float*)d_out;
    float* hnew   = logits + (size_t)B_ * V_;
    float* attnw  = hnew + (size_t)B_ * H_;

    float* ws       = (float*)d_ws;
    float* partials = ws;                                  // 262144 f
    float* E1       = partials + 262144;                   // 262144 f
    float* gi       = E1 + 262144;                         // 786432 f
    float* gh       = gi + 786432;                         // 786432 f
    short* h_bf     = (short*)(gh + 786432);               // 262144 sh
    short* xgi_bf   = h_bf + 262144;                       // 655360 sh
    short* xlo_bf   = xgi_bf + 655360;                     // 917504 sh
    short* Wattn2   = xlo_bf + 917504;                     // 2097152 sh

    conv_static<<<384, 256, 0, stream>>>(hidden, input_emb, h_bf, xgi_bf, xlo_bf);
    conv_wattn2<<<2048, 256, 0, stream>>>(W_attn, Wattn2);

    // E1 (n<1024, no bias) + gh (n>=1024, +b_hh), X = h_bf
    gemm2<1><<<32, 512, 0, stream>>>(h_bf, 1024, 1024,
                                     W_attn, 3072, W_hh, b_hh, E1, 1024, gh);
    // energy
    {
        dim3 grid(4, 128);
        energy2<<<grid, 512, 0, stream>>>(enc, Wattn2, E1, b_attn, v_attn, partials);
    }
    softmax_k<<<B_, 64, 0, stream>>>(partials, mask, attnw);
    weighted2<<<B_, 256, 0, stream>>>(attnw, enc, xgi_bf, xlo_bf);
    // gi = xgi_bf * W_ih^T + b_ih
    gemm2<0><<<24, 512, 0, stream>>>(xgi_bf, 2560, 2560,
                                     W_ih, 2560, nullptr, b_ih, gi, 3072, nullptr);
    gru2<<<1024, 256, 0, stream>>>(gi, gh, hidden, hnew, xlo_bf);
    // logits = xlo_bf * W_out^T + b_out
    gemm2<0><<<250, 512, 0, stream>>>(xlo_bf, 3584, 3584,
                                      W_out, 3584, nullptr, b_out, logits, 32000, nullptr);
}

// Round 5
// 432.035 us; speedup vs baseline: 8.7677x; 1.2735x over previous
//
#include <hip/hip_runtime.h>
#include <cstddef>

static constexpr int B_  = 256;
static constexpr int L_  = 64;
static constexpr int H_  = 1024;
static constexpr int IN_ = 512;
static constexpr int V_  = 32000;

typedef __attribute__((ext_vector_type(8))) short bf8;
typedef __attribute__((ext_vector_type(4))) short s4;
typedef __attribute__((ext_vector_type(4))) float f32x4;

__device__ __forceinline__ short f2b(float x) {
    unsigned u = __float_as_uint(x);
    u += 0x7fffu + ((u >> 16) & 1u);
    return (short)(u >> 16);
}
__device__ __forceinline__ bf8 pack8(const float4& a, const float4& b) {
    bf8 r;
    r[0]=f2b(a.x); r[1]=f2b(a.y); r[2]=f2b(a.z); r[3]=f2b(a.w);
    r[4]=f2b(b.x); r[5]=f2b(b.y); r[6]=f2b(b.z); r[7]=f2b(b.w);
    return r;
}

// ---------------- conversion kernels ----------------
__global__ __launch_bounds__(256) void conv_static(
    const float* __restrict__ h, const float* __restrict__ emb,
    short* __restrict__ h_bf, short* __restrict__ xgi, short* __restrict__ xlo)
{
    int u = blockIdx.x * 256 + threadIdx.x;          // float4 units
    if (u < 65536) {                                  // h: 256*1024/4
        float4 f = *(const float4*)(h + (size_t)u * 4);
        s4 s; s[0]=f2b(f.x); s[1]=f2b(f.y); s[2]=f2b(f.z); s[3]=f2b(f.w);
        *(s4*)(h_bf + (size_t)u * 4) = s;
    } else {                                          // emb: 256*512/4 = 32768
        int e = u - 65536;
        int m = e >> 7, c4 = (e & 127) * 4;
        float4 f = *(const float4*)(emb + (size_t)m * 512 + c4);
        s4 s; s[0]=f2b(f.x); s[1]=f2b(f.y); s[2]=f2b(f.z); s[3]=f2b(f.w);
        *(s4*)(xgi + (size_t)m * 2560 + c4) = s;
        *(s4*)(xlo + (size_t)m * 3584 + 3072 + c4) = s;
    }
}

__global__ __launch_bounds__(256) void conv_wattn2(
    const float* __restrict__ W_attn, short* __restrict__ Wb)
{
    int o = blockIdx.x * 256 + threadIdx.x;           // float4 units, 524288
    int r = o >> 9, c4 = (o & 511) * 4;
    float4 f = *(const float4*)(W_attn + (size_t)r * 3072 + 1024 + c4);
    s4 s; s[0]=f2b(f.x); s[1]=f2b(f.y); s[2]=f2b(f.z); s[3]=f2b(f.w);
    *(s4*)(Wb + (size_t)r * 2048 + c4) = s;
}

// ---------------- GEMM: C[256,N] = Xb[256,K](bf16) * W[N,K](f32)^T ----------------
// BM=256, BN=64, BK=64. 256 thr = 4 waves, wave tile 64(rows)x64(cols).
// LDS = 32KB X + 8KB W = 40KB -> 4 blocks/CU.
// MODE 0: plain.  MODE 1: combo E1(n<1024, no bias) + gh(n>=1024, +b_hh).
template<int MODE>
__global__ __launch_bounds__(256) void gemm3(
    const short* __restrict__ Xb, int ldx, int K,
    const float* __restrict__ W0, int ldw0,
    const float* __restrict__ W1,
    const float* __restrict__ bias,
    float* __restrict__ out0, int ldo0,
    float* __restrict__ out1)
{
    __shared__ short Xs[256 * 64];
    __shared__ short Ws[64 * 64];

    const int tid = threadIdx.x;
    const int n0 = blockIdx.x * 64;
    const int wid = tid >> 6, lane = tid & 63;
    const int ln15 = lane & 15, kq = lane >> 4;

    const float* Wsrc; int ldw;
    if (MODE == 1) {
        if (n0 < 1024) { Wsrc = W0 + (size_t)n0 * ldw0; ldw = ldw0; }
        else           { Wsrc = W1 + (size_t)(n0 - 1024) * 1024; ldw = 1024; }
    } else { Wsrc = W0 + (size_t)n0 * ldw0; ldw = ldw0; }

    // X staging: 2048 chunks of 8 bf16, 8/thread
    int xdst[8]; const short* xsrc[8];
    #pragma unroll
    for (int c = 0; c < 8; ++c) {
        int o = c * 256 + tid;
        int row = o >> 3, cb = o & 7;
        xsrc[c] = Xb + (size_t)row * ldx + cb * 8;
        xdst[c] = row * 64 + ((cb * 8) ^ ((row & 7) << 3));
    }
    // W staging: 64 rows x 64 f32 = 512 groups of 8, 2/thread
    int wdst[2]; const float* wsrcp[2];
    #pragma unroll
    for (int g = 0; g < 2; ++g) {
        int o = g * 256 + tid;
        int row = o >> 3, gb = o & 7;
        wsrcp[g] = Wsrc + (size_t)row * ldw + gb * 8;
        wdst[g] = row * 64 + ((gb * 8) ^ ((row & 7) << 3));
    }
    // fragment offsets
    int aoff[2][4], boff[2][4];
    #pragma unroll
    for (int ks = 0; ks < 2; ++ks) {
        #pragma unroll
        for (int i = 0; i < 4; ++i) {
            int ar = wid * 64 + i * 16 + ln15;
            aoff[ks][i] = ar * 64 + ((ks * 32 + kq * 8) ^ ((ar & 7) << 3));
            int br = i * 16 + ln15;
            boff[ks][i] = br * 64 + ((ks * 32 + kq * 8) ^ ((br & 7) << 3));
        }
    }

    f32x4 acc[4][4];
    #pragma unroll
    for (int i = 0; i < 4; ++i)
        #pragma unroll
        for (int j = 0; j < 4; ++j) acc[i][j] = {0.f, 0.f, 0.f, 0.f};

    bf8 xA[8], xB[8];
    float4 wA[4], wB[4];

    const int NT = K >> 6;

    #pragma unroll
    for (int c = 0; c < 8; ++c) xA[c] = *(const bf8*)(xsrc[c]);
    #pragma unroll
    for (int g = 0; g < 2; ++g) {
        wA[2*g]   = *(const float4*)(wsrcp[g]);
        wA[2*g+1] = *(const float4*)(wsrcp[g] + 4);
    }

    for (int t = 0; t < NT; t += 2) {
        // half 1: store A, prefetch B(t+1), compute
        __syncthreads();
        #pragma unroll
        for (int c = 0; c < 8; ++c) *(bf8*)&Xs[xdst[c]] = xA[c];
        #pragma unroll
        for (int g = 0; g < 2; ++g) *(bf8*)&Ws[wdst[g]] = pack8(wA[2*g], wA[2*g+1]);
        if (t + 1 < NT) {
            int k0 = (t + 1) << 6;
            #pragma unroll
            for (int c = 0; c < 8; ++c) xB[c] = *(const bf8*)(xsrc[c] + k0);
            #pragma unroll
            for (int g = 0; g < 2; ++g) {
                wB[2*g]   = *(const float4*)(wsrcp[g] + k0);
                wB[2*g+1] = *(const float4*)(wsrcp[g] + k0 + 4);
            }
        }
        __syncthreads();
        #pragma unroll
        for (int ks = 0; ks < 2; ++ks) {
            bf8 a[4], b[4];
            #pragma unroll
            for (int i = 0; i < 4; ++i) a[i] = *(const bf8*)&Xs[aoff[ks][i]];
            #pragma unroll
            for (int j = 0; j < 4; ++j) b[j] = *(const bf8*)&Ws[boff[ks][j]];
            #pragma unroll
            for (int i = 0; i < 4; ++i)
                #pragma unroll
                for (int j = 0; j < 4; ++j)
                    acc[i][j] = __builtin_amdgcn_mfma_f32_16x16x32_bf16(a[i], b[j], acc[i][j], 0, 0, 0);
        }
        if (t + 1 >= NT) break;
        // half 2: store B, prefetch A(t+2), compute
        __syncthreads();
        #pragma unroll
        for (int c = 0; c < 8; ++c) *(bf8*)&Xs[xdst[c]] = xB[c];
        #pragma unroll
        for (int g = 0; g < 2; ++g) *(bf8*)&Ws[wdst[g]] = pack8(wB[2*g], wB[2*g+1]);
        if (t + 2 < NT) {
            int k0 = (t + 2) << 6;
            #pragma unroll
            for (int c = 0; c < 8; ++c) xA[c] = *(const bf8*)(xsrc[c] + k0);
            #pragma unroll
            for (int g = 0; g < 2; ++g) {
                wA[2*g]   = *(const float4*)(wsrcp[g] + k0);
                wA[2*g+1] = *(const float4*)(wsrcp[g] + k0 + 4);
            }
        }
        __syncthreads();
        #pragma unroll
        for (int ks = 0; ks < 2; ++ks) {
            bf8 a[4], b[4];
            #pragma unroll
            for (int i = 0; i < 4; ++i) a[i] = *(const bf8*)&Xs[aoff[ks][i]];
            #pragma unroll
            for (int j = 0; j < 4; ++j) b[j] = *(const bf8*)&Ws[boff[ks][j]];
            #pragma unroll
            for (int i = 0; i < 4; ++i)
                #pragma unroll
                for (int j = 0; j < 4; ++j)
                    acc[i][j] = __builtin_amdgcn_mfma_f32_16x16x32_bf16(a[i], b[j], acc[i][j], 0, 0, 0);
        }
    }

    // epilogue: C/D map col=lane&15, row=(lane>>4)*4+r
    #pragma unroll
    for (int i = 0; i < 4; ++i) {
        #pragma unroll
        for (int j = 0; j < 4; ++j) {
            int col = n0 + j * 16 + ln15;
            #pragma unroll
            for (int r = 0; r < 4; ++r) {
                int row = wid * 64 + i * 16 + kq * 4 + r;
                float v = acc[i][j][r];
                if (MODE == 1) {
                    if (n0 < 1024) out0[(size_t)row * ldo0 + col] = v;
                    else           out1[(size_t)row * 3072 + (col - 1024)] = v + bias[col - 1024];
                } else {
                    out0[(size_t)row * ldo0 + col] = v + (bias ? bias[col] : 0.f);
                }
            }
        }
    }
}

// ---------------- energy: E2 = enc(f32->bf16) * Wattn2_bf^T, fused tanh/v epilogue ----------------
// BM=128, BN=256, BK=64. 512 logical blocks, XCD-chunk swizzled. 8 waves (2 row x 4 col).
__global__ __launch_bounds__(512, 2) void energy2(
    const float* __restrict__ enc,
    const short* __restrict__ Wb,       // [1024][2048] bf16
    const float* __restrict__ E1,       // [256][1024]
    const float* __restrict__ b_attn,
    const float* __restrict__ v_attn,
    float* __restrict__ partials)       // [16384][16]
{
    __shared__ short Xs[128 * 64];
    __shared__ short Ws[256 * 64];

    const int tid = threadIdx.x;
    // XCD-chunk swizzle: 4 nb-siblings (same enc rows) land on the same XCD consecutively
    const int p = blockIdx.x;                    // 0..511
    const int logical = (p & 7) * 64 + (p >> 3); // bijective
    const int nb = logical & 3, n0 = nb * 256;
    const int m0 = (logical >> 2) * 128;
    const int wid = tid >> 6, lane = tid & 63;
    const int wrow = wid >> 2, wcol = wid & 3;
    const int ln15 = lane & 15, kq = lane >> 4;

    int xdst[2]; const float* xsrc[2];
    #pragma unroll
    for (int g = 0; g < 2; ++g) {
        int o = g * 512 + tid;
        int row = o >> 3, gb = o & 7;
        int m = m0 + row, b = m >> 6, l = m & 63;
        xsrc[g] = enc + ((size_t)l * B_ + b) * 2048 + gb * 8;
        xdst[g] = row * 64 + ((gb * 8) ^ ((row & 7) << 3));
    }
    int wdst[4]; const short* wsrcp[4];
    #pragma unroll
    for (int c = 0; c < 4; ++c) {
        int o = c * 512 + tid;
        int row = o >> 3, cb = o & 7;
        wsrcp[c] = Wb + (size_t)(n0 + row) * 2048 + cb * 8;
        wdst[c] = row * 64 + ((cb * 8) ^ ((row & 7) << 3));
    }
    int aoff[2][4], boff[2][4];
    #pragma unroll
    for (int ks = 0; ks < 2; ++ks) {
        #pragma unroll
        for (int i = 0; i < 4; ++i) {
            int ar = wrow * 64 + i * 16 + ln15;
            aoff[ks][i] = ar * 64 + ((ks * 32 + kq * 8) ^ ((ar & 7) << 3));
            int br = wcol * 64 + i * 16 + ln15;
            boff[ks][i] = br * 64 + ((ks * 32 + kq * 8) ^ ((br & 7) << 3));
        }
    }

    f32x4 acc[4][4];
    #pragma unroll
    for (int i = 0; i < 4; ++i)
        #pragma unroll
        for (int j = 0; j < 4; ++j) acc[i][j] = {0.f, 0.f, 0.f, 0.f};

    float4 xA[4], xB[4];
    bf8 wA[4], wB[4];

    const int NT = 32;  // K = 2048

    #pragma unroll
    for (int g = 0; g < 2; ++g) {
        xA[2*g]   = *(const float4*)(xsrc[g]);
        xA[2*g+1] = *(const float4*)(xsrc[g] + 4);
    }
    #pragma unroll
    for (int c = 0; c < 4; ++c) wA[c] = *(const bf8*)(wsrcp[c]);

    for (int t = 0; t < NT; t += 2) {
        __syncthreads();
        #pragma unroll
        for (int g = 0; g < 2; ++g) *(bf8*)&Xs[xdst[g]] = pack8(xA[2*g], xA[2*g+1]);
        #pragma unroll
        for (int c = 0; c < 4; ++c) *(bf8*)&Ws[wdst[c]] = wA[c];
        {
            int k0 = (t + 1) << 6;
            #pragma unroll
            for (int g = 0; g < 2; ++g) {
                xB[2*g]   = *(const float4*)(xsrc[g] + k0);
                xB[2*g+1] = *(const float4*)(xsrc[g] + k0 + 4);
            }
            #pragma unroll
            for (int c = 0; c < 4; ++c) wB[c] = *(const bf8*)(wsrcp[c] + k0);
        }
        __syncthreads();
        #pragma unroll
        for (int ks = 0; ks < 2; ++ks) {
            bf8 a[4], b[4];
            #pragma unroll
            for (int i = 0; i < 4; ++i) a[i] = *(const bf8*)&Xs[aoff[ks][i]];
            #pragma unroll
            for (int j = 0; j < 4; ++j) b[j] = *(const bf8*)&Ws[boff[ks][j]];
            #pragma unroll
            for (int i = 0; i < 4; ++i)
                #pragma unroll
                for (int j = 0; j < 4; ++j)
                    acc[i][j] = __builtin_amdgcn_mfma_f32_16x16x32_bf16(a[i], b[j], acc[i][j], 0, 0, 0);
        }
        __syncthreads();
        #pragma unroll
        for (int g = 0; g < 2; ++g) *(bf8*)&Xs[xdst[g]] = pack8(xB[2*g], xB[2*g+1]);
        #pragma unroll
        for (int c = 0; c < 4; ++c) *(bf8*)&Ws[wdst[c]] = wB[c];
        if (t + 2 < NT) {
            int k0 = (t + 2) << 6;
            #pragma unroll
            for (int g = 0; g < 2; ++g) {
                xA[2*g]   = *(const float4*)(xsrc[g] + k0);
                xA[2*g+1] = *(const float4*)(xsrc[g] + k0 + 4);
            }
            #pragma unroll
            for (int c = 0; c < 4; ++c) wA[c] = *(const bf8*)(wsrcp[c] + k0);
        }
        __syncthreads();
        #pragma unroll
        for (int ks = 0; ks < 2; ++ks) {
            bf8 a[4], b[4];
            #pragma unroll
            for (int i = 0; i < 4; ++i) a[i] = *(const bf8*)&Xs[aoff[ks][i]];
            #pragma unroll
            for (int j = 0; j < 4; ++j) b[j] = *(const bf8*)&Ws[boff[ks][j]];
            #pragma unroll
            for (int i = 0; i < 4; ++i)
                #pragma unroll
                for (int j = 0; j < 4; ++j)
                    acc[i][j] = __builtin_amdgcn_mfma_f32_16x16x32_bf16(a[i], b[j], acc[i][j], 0, 0, 0);
        }
    }

    float rs[4][4];
    #pragma unroll
    for (int i = 0; i < 4; ++i)
        #pragma unroll
        for (int r = 0; r < 4; ++r) rs[i][r] = 0.f;

    #pragma unroll
    for (int i = 0; i < 4; ++i) {
        #pragma unroll
        for (int j = 0; j < 4; ++j) {
            int col = n0 + wcol * 64 + j * 16 + ln15;
            float bv = b_attn[col], vv = v_attn[col];
            #pragma unroll
            for (int r = 0; r < 4; ++r) {
                int m = m0 + wrow * 64 + i * 16 + kq * 4 + r;
                float e = tanhf(acc[i][j][r] + E1[(size_t)(m >> 6) * 1024 + col] + bv);
                rs[i][r] += e * vv;
            }
        }
    }
    #pragma unroll
    for (int i = 0; i < 4; ++i)
        #pragma unroll
        for (int r = 0; r < 4; ++r) {
            float s = rs[i][r];
            #pragma unroll
            for (int off = 1; off < 16; off <<= 1) s += __shfl_xor(s, off);
            rs[i][r] = s;
        }
    if (ln15 == 0) {
        #pragma unroll
        for (int i = 0; i < 4; ++i)
            #pragma unroll
            for (int r = 0; r < 4; ++r) {
                int m = m0 + wrow * 64 + i * 16 + kq * 4 + r;
                partials[(size_t)m * 16 + nb * 4 + wcol] = rs[i][r];
            }
    }
}

// masked softmax over L=64
__global__ __launch_bounds__(64) void softmax_k(const float* __restrict__ partials,
                                                const int* __restrict__ mask,
                                                float* __restrict__ attnw)
{
    int b = blockIdx.x;
    int l = threadIdx.x;
    float s = 0.f;
    #pragma unroll
    for (int nb = 0; nb < 16; ++nb) s += partials[(size_t)(b * 64 + l) * 16 + nb];
    if (mask[b * 64 + l] != 0) s = -1e10f;
    float m = s;
    #pragma unroll
    for (int off = 32; off; off >>= 1) m = fmaxf(m, __shfl_xor(m, off));
    float e = expf(s - m);
    float sum = e;
    #pragma unroll
    for (int off = 32; off; off >>= 1) sum += __shfl_xor(sum, off);
    attnw[b * 64 + l] = e / sum;
}

// weighted -> bf16 into xgi_bf[:,512:2560] and xlo_bf[:,1024:3072]; float4 loads
__global__ __launch_bounds__(512) void weighted2(const float* __restrict__ attnw,
                                                 const float* __restrict__ enc,
                                                 short* __restrict__ xgi,
                                                 short* __restrict__ xlo)
{
    int b = blockIdx.x;
    int t = threadIdx.x;           // 512 threads x 4 floats = 2048
    float4 acc = {0.f, 0.f, 0.f, 0.f};
    const float* base = enc + (size_t)b * 2048 + t * 4;
    for (int l = 0; l < 64; ++l) {
        float w = attnw[b * 64 + l];
        float4 f = *(const float4*)(base + (size_t)l * B_ * 2048);
        acc.x += w * f.x; acc.y += w * f.y; acc.z += w * f.z; acc.w += w * f.w;
    }
    s4 s; s[0]=f2b(acc.x); s[1]=f2b(acc.y); s[2]=f2b(acc.z); s[3]=f2b(acc.w);
    *(s4*)(xgi + (size_t)b * 2560 + 512 + t * 4) = s;
    *(s4*)(xlo + (size_t)b * 3584 + 1024 + t * 4) = s;
}

// GRU gates; writes hnew (f32 output) and xlo_bf[:,0:1024]
__global__ __launch_bounds__(256) void gru2(const float* __restrict__ gi,
                                            const float* __restrict__ gh,
                                            const float* __restrict__ h,
                                            float* __restrict__ hnew,
                                            short* __restrict__ xlo)
{
    int idx = blockIdx.x * 256 + threadIdx.x;
    int b = idx >> 10, j = idx & 1023;
    const float* gib = gi + (size_t)b * 3072;
    const float* ghb = gh + (size_t)b * 3072;
    float r = 1.f / (1.f + expf(-(gib[j] + ghb[j])));
    float z = 1.f / (1.f + expf(-(gib[1024 + j] + ghb[1024 + j])));
    float n = tanhf(gib[2048 + j] + r * ghb[2048 + j]);
    float hv = (1.f - z) * n + z * h[idx];
    hnew[idx] = hv;
    xlo[(size_t)b * 3584 + j] = f2b(hv);
}

extern "C" void kernel_launch(void* const* d_in, const int* in_sizes, int n_in,
                              void* d_out, int out_size, void* d_ws, size_t ws_size,
                              hipStream_t stream) {
    const float* input_emb = (const float*)d_in[0];
    const float* hidden    = (const float*)d_in[1];
    const float* enc       = (const float*)d_in[2];
    const int*   mask      = (const int*)d_in[3];
    const float* W_attn = (const float*)d_in[4];
    const float* b_attn = (const float*)d_in[5];
    const float* v_attn = (const float*)d_in[6];
    const float* W_ih   = (const float*)d_in[7];
    const float* W_hh   = (const float*)d_in[8];
    const float* b_ih   = (const float*)d_in[9];
    const float* b_hh   = (const float*)d_in[10];
    const float* W_out  = (const float*)d_in[11];
    const float* b_out  = (const float*)d_in[12];

    float* logits = (float*)d_out;
    float* hnew   = logits + (size_t)B_ * V_;
    float* attnw  = hnew + (size_t)B_ * H_;

    float* ws       = (float*)d_ws;
    float* partials = ws;                                  // 262144 f
    float* E1       = partials + 262144;                   // 262144 f
    float* gi       = E1 + 262144;                         // 786432 f
    float* gh       = gi + 786432;                         // 786432 f
    short* h_bf     = (short*)(gh + 786432);               // 262144 sh
    short* xgi_bf   = h_bf + 262144;                       // 655360 sh
    short* xlo_bf   = xgi_bf + 655360;                     // 917504 sh
    short* Wattn2   = xlo_bf + 917504;                     // 2097152 sh

    conv_static<<<384, 256, 0, stream>>>(hidden, input_emb, h_bf, xgi_bf, xlo_bf);
    conv_wattn2<<<2048, 256, 0, stream>>>(W_attn, Wattn2);

    // E1 (n<1024, no bias) + gh (n>=1024, +b_hh), X = h_bf
    gemm3<1><<<64, 256, 0, stream>>>(h_bf, 1024, 1024,
                                     W_attn, 3072, W_hh, b_hh, E1, 1024, gh);
    // energy (512 blocks, XCD-swizzled internally)
    energy2<<<512, 512, 0, stream>>>(enc, Wattn2, E1, b_attn, v_attn, partials);
    softmax_k<<<B_, 64, 0, stream>>>(partials, mask, attnw);
    weighted2<<<B_, 512, 0, stream>>>(attnw, enc, xgi_bf, xlo_bf);
    // gi = xgi_bf * W_ih^T + b_ih
    gemm3<0><<<48, 256, 0, stream>>>(xgi_bf, 2560, 2560,
                                     W_ih, 2560, nullptr, b_ih, gi, 3072, nullptr);
    gru2<<<1024, 256, 0, stream>>>(gi, gh, hidden, hnew, xlo_bf);
    // logits = xlo_bf * W_out^T + b_out
    gemm3<0><<<500, 256, 0, stream>>>(xlo_bf, 3584, 3584,
                                      W_out, 3584, nullptr, b_out, logits, 32000, nullptr);
}